// Round 2
// baseline (750.500 us; speedup 1.0000x reference)
//
#include <hip/hip_runtime.h>
#include <math.h>

// 2-layer GCN, N=100000, E=1.6M, DIN=256, HID=DOUT=64.
// L(x) = dinv ⊙ (A_w @ (dinv ⊙ (x@W))) + b, A_w incl. self-loops (w=1),
// dinv = rsqrt(deg_w + 1). Strategy: g = dinv*(x@W) via register-tiled fp32
// GEMM; CSR (dst-sorted) pull for the scatter-add (no float atomics).

#define GCN_DIN 256
#define GCN_HID 64

// ---------- CSR build ----------
__global__ void count_kernel(const int* __restrict__ dst, int* __restrict__ counts, int E) {
    int e = blockIdx.x * blockDim.x + threadIdx.x;
    if (e < E) atomicAdd(&counts[dst[e]], 1);
}

#define SCAN_T 1024
__global__ __launch_bounds__(SCAN_T) void scan_kernel(const int* __restrict__ counts,
                                                      int* __restrict__ rowptr, int N) {
    __shared__ int sums[SCAN_T];
    int t = threadIdx.x;
    int chunk = (N + SCAN_T - 1) / SCAN_T;
    int begin = t * chunk; if (begin > N) begin = N;
    int end = begin + chunk; if (end > N) end = N;
    int s = 0;
    for (int i = begin; i < end; ++i) s += counts[i];
    sums[t] = s;
    __syncthreads();
    for (int off = 1; off < SCAN_T; off <<= 1) {
        int v = (t >= off) ? sums[t - off] : 0;
        __syncthreads();
        sums[t] += v;
        __syncthreads();
    }
    int excl = (t == 0) ? 0 : sums[t - 1];
    for (int i = begin; i < end; ++i) {
        rowptr[i] = excl;
        excl += counts[i];
    }
    if (t == SCAN_T - 1) rowptr[N] = excl;
}

__global__ void copy_int_kernel(const int* __restrict__ a, int* __restrict__ b, int N) {
    int i = blockIdx.x * blockDim.x + threadIdx.x;
    if (i < N) b[i] = a[i];
}

__global__ void reorder_kernel(const int* __restrict__ src, const int* __restrict__ dst,
                               const float* __restrict__ ew, int* __restrict__ cursor,
                               int2* __restrict__ comb, int E) {
    int e = blockIdx.x * blockDim.x + threadIdx.x;
    if (e < E) {
        int d = dst[e];
        int pos = atomicAdd(&cursor[d], 1);
        comb[pos] = make_int2(src[e], __float_as_int(ew[e]));
    }
}

// dinv[n] = rsqrt(1 + sum of incoming ew)
__global__ void degw_kernel(const int* __restrict__ rowptr, const int2* __restrict__ comb,
                            float* __restrict__ dinv, int N) {
    int n = blockIdx.x * blockDim.x + threadIdx.x;
    if (n >= N) return;
    float s = 1.0f;
    int je = rowptr[n + 1];
    for (int j = rowptr[n]; j < je; ++j) s += __int_as_float(comb[j].y);
    dinv[n] = (s > 0.f) ? (1.0f / sqrtf(s)) : 0.f;
}

// ---------- GEMM1: g = dinv * (x @ W1), [N,256]x[256,64] ----------
// 64 rows/block, 256 threads, thread = 4x4 outputs, k-major LDS tiles, b128 reads.
__global__ __launch_bounds__(256) void gemm1_kernel(
    const float* __restrict__ x, const float* __restrict__ W,
    const float* __restrict__ dinv, float* __restrict__ g, int N)
{
    __shared__ float xs[32][68];   // [k][row], pad 68 keeps 16B align, spreads banks
    __shared__ float ws[32][64];   // [k][col]
    const int tid = threadIdx.x;
    const int tx = tid & 15;       // col group (cols tx*4..+3)
    const int ty = tid >> 4;       // row group (rows ty*4..+3)
    const int row0 = blockIdx.x * 64;

    float acc[4][4];
    #pragma unroll
    for (int i = 0; i < 4; ++i)
        #pragma unroll
        for (int j = 0; j < 4; ++j) acc[i][j] = 0.f;

    for (int k0 = 0; k0 < GCN_DIN; k0 += 32) {
        // stage x tile 64 rows x 32 k, transposed to k-major
        {
            int kc = tid & 7;      // k chunk (*4)
            int r  = tid >> 3;     // 0..31
            #pragma unroll
            for (int h = 0; h < 2; ++h) {
                int rr = r + 32 * h;
                int row = row0 + rr;
                float4 v = make_float4(0.f, 0.f, 0.f, 0.f);
                if (row < N) v = *(const float4*)&x[(size_t)row * GCN_DIN + k0 + kc * 4];
                xs[kc * 4 + 0][rr] = v.x;
                xs[kc * 4 + 1][rr] = v.y;
                xs[kc * 4 + 2][rr] = v.z;
                xs[kc * 4 + 3][rr] = v.w;
            }
        }
        // stage W tile 32 k x 64 col (already k-major)
        {
            int c  = tid & 63;
            int kr = tid >> 6;     // 0..3
            #pragma unroll
            for (int h = 0; h < 8; ++h)
                ws[kr + 4 * h][c] = W[(size_t)(k0 + kr + 4 * h) * 64 + c];
        }
        __syncthreads();
        #pragma unroll
        for (int kk = 0; kk < 32; ++kk) {
            float4 a = *(const float4*)&xs[kk][ty * 4];
            float4 b = *(const float4*)&ws[kk][tx * 4];
            float av[4] = {a.x, a.y, a.z, a.w};
            float bv[4] = {b.x, b.y, b.z, b.w};
            #pragma unroll
            for (int i = 0; i < 4; ++i)
                #pragma unroll
                for (int j = 0; j < 4; ++j)
                    acc[i][j] = fmaf(av[i], bv[j], acc[i][j]);
        }
        __syncthreads();
    }
    #pragma unroll
    for (int i = 0; i < 4; ++i) {
        int row = row0 + ty * 4 + i;
        if (row < N) {
            float dv = dinv[row];
            float4 o = make_float4(dv * acc[i][0], dv * acc[i][1],
                                   dv * acc[i][2], dv * acc[i][3]);
            *(float4*)&g[(size_t)row * 64 + tx * 4] = o;
        }
    }
}

// ---------- GEMM2: g = dinv * (relu(dinv*acc1 + b1) @ W2), K=64 ----------
__global__ __launch_bounds__(256) void gemm2_kernel(
    const float* __restrict__ acc1, const float* __restrict__ W,
    const float* __restrict__ dinv, const float* __restrict__ b1,
    float* __restrict__ g, int N)
{
    __shared__ float xs[32][68];
    __shared__ float ws[32][64];
    const int tid = threadIdx.x;
    const int tx = tid & 15;
    const int ty = tid >> 4;
    const int row0 = blockIdx.x * 64;

    float acc[4][4];
    #pragma unroll
    for (int i = 0; i < 4; ++i)
        #pragma unroll
        for (int j = 0; j < 4; ++j) acc[i][j] = 0.f;

    for (int k0 = 0; k0 < GCN_HID; k0 += 32) {
        {
            int kc = tid & 7;
            int r  = tid >> 3;
            float4 bb = *(const float4*)&b1[k0 + kc * 4];
            #pragma unroll
            for (int h = 0; h < 2; ++h) {
                int rr = r + 32 * h;
                int row = row0 + rr;
                float4 v = make_float4(0.f, 0.f, 0.f, 0.f);
                if (row < N) {
                    float dv = dinv[row];
                    float4 hh = *(const float4*)&acc1[(size_t)row * 64 + k0 + kc * 4];
                    v.x = fmaxf(dv * hh.x + bb.x, 0.f);
                    v.y = fmaxf(dv * hh.y + bb.y, 0.f);
                    v.z = fmaxf(dv * hh.z + bb.z, 0.f);
                    v.w = fmaxf(dv * hh.w + bb.w, 0.f);
                }
                xs[kc * 4 + 0][rr] = v.x;
                xs[kc * 4 + 1][rr] = v.y;
                xs[kc * 4 + 2][rr] = v.z;
                xs[kc * 4 + 3][rr] = v.w;
            }
        }
        {
            int c  = tid & 63;
            int kr = tid >> 6;
            #pragma unroll
            for (int h = 0; h < 8; ++h)
                ws[kr + 4 * h][c] = W[(size_t)(k0 + kr + 4 * h) * 64 + c];
        }
        __syncthreads();
        #pragma unroll
        for (int kk = 0; kk < 32; ++kk) {
            float4 a = *(const float4*)&xs[kk][ty * 4];
            float4 b = *(const float4*)&ws[kk][tx * 4];
            float av[4] = {a.x, a.y, a.z, a.w};
            float bv[4] = {b.x, b.y, b.z, b.w};
            #pragma unroll
            for (int i = 0; i < 4; ++i)
                #pragma unroll
                for (int j = 0; j < 4; ++j)
                    acc[i][j] = fmaf(av[i], bv[j], acc[i][j]);
        }
        __syncthreads();
    }
    #pragma unroll
    for (int i = 0; i < 4; ++i) {
        int row = row0 + ty * 4 + i;
        if (row < N) {
            float dv = dinv[row];
            float4 o = make_float4(dv * acc[i][0], dv * acc[i][1],
                                   dv * acc[i][2], dv * acc[i][3]);
            *(float4*)&g[(size_t)row * 64 + tx * 4] = o;
        }
    }
}

// ---------- pull: out[n] = g[n] (self-loop) + sum_in ew * g[src]; wave per node ----------
__global__ __launch_bounds__(256) void pull_kernel(
    const int* __restrict__ rowptr, const int2* __restrict__ comb,
    const float* __restrict__ g, float* __restrict__ out, int N)
{
    int wid  = (blockIdx.x * blockDim.x + threadIdx.x) >> 6;
    int lane = threadIdx.x & 63;
    if (wid >= N) return;
    int jb = rowptr[wid], je = rowptr[wid + 1];
    float acc = g[(size_t)wid * 64 + lane];
    int j = jb;
    for (; j + 1 < je; j += 2) {
        int2 e0 = comb[j], e1 = comb[j + 1];
        float v0 = g[(size_t)e0.x * 64 + lane];
        float v1 = g[(size_t)e1.x * 64 + lane];
        acc = fmaf(__int_as_float(e0.y), v0, acc);
        acc = fmaf(__int_as_float(e1.y), v1, acc);
    }
    if (j < je) {
        int2 e0 = comb[j];
        acc = fmaf(__int_as_float(e0.y), g[(size_t)e0.x * 64 + lane], acc);
    }
    out[(size_t)wid * 64 + lane] = acc;
}

// same, fused final epilogue: out = dinv[n]*acc + b2
__global__ __launch_bounds__(256) void pull_final_kernel(
    const int* __restrict__ rowptr, const int2* __restrict__ comb,
    const float* __restrict__ g, const float* __restrict__ dinv,
    const float* __restrict__ b2, float* __restrict__ out, int N)
{
    int wid  = (blockIdx.x * blockDim.x + threadIdx.x) >> 6;
    int lane = threadIdx.x & 63;
    if (wid >= N) return;
    int jb = rowptr[wid], je = rowptr[wid + 1];
    float acc = g[(size_t)wid * 64 + lane];
    int j = jb;
    for (; j + 1 < je; j += 2) {
        int2 e0 = comb[j], e1 = comb[j + 1];
        float v0 = g[(size_t)e0.x * 64 + lane];
        float v1 = g[(size_t)e1.x * 64 + lane];
        acc = fmaf(__int_as_float(e0.y), v0, acc);
        acc = fmaf(__int_as_float(e1.y), v1, acc);
    }
    if (j < je) {
        int2 e0 = comb[j];
        acc = fmaf(__int_as_float(e0.y), g[(size_t)e0.x * 64 + lane], acc);
    }
    out[(size_t)wid * 64 + lane] = dinv[wid] * acc + b2[lane];
}

extern "C" void kernel_launch(void* const* d_in, const int* in_sizes, int n_in,
                              void* d_out, int out_size, void* d_ws, size_t ws_size,
                              hipStream_t stream) {
    const float* x  = (const float*)d_in[0];
    const int*   ei = (const int*)  d_in[1];
    const float* ew = (const float*)d_in[2];
    const float* W1 = (const float*)d_in[3];
    const float* b1 = (const float*)d_in[4];
    const float* W2 = (const float*)d_in[5];
    const float* b2 = (const float*)d_in[6];
    float* out = (float*)d_out;

    const int N = in_sizes[0] / GCN_DIN;   // 100000
    const int E = in_sizes[1] / 2;         // 1600000
    const int* src = ei;
    const int* dst = ei + E;

    // workspace layout (8B-aligned order): comb | B1 | B2 | dinv | counts | cursor | rowptr
    char* p = (char*)d_ws;
    int2*  comb   = (int2*)p;  p += (size_t)E * sizeof(int2);
    float* B1     = (float*)p; p += (size_t)N * 64 * sizeof(float);
    float* B2     = (float*)p; p += (size_t)N * 64 * sizeof(float);
    float* dinv   = (float*)p; p += (size_t)N * sizeof(float);
    int*   counts = (int*)p;   p += (size_t)N * sizeof(int);
    int*   cursor = (int*)p;   p += (size_t)N * sizeof(int);
    int*   rowptr = (int*)p;   p += (size_t)(N + 1) * sizeof(int);

    const int eBlocks = (E + 255) / 256;
    const int nBlocks = (N + 255) / 256;
    const int gBlocks = (N + 63) / 64;
    const int wBlocks = (N + 3) / 4;       // 4 waves/block, 1 node/wave

    // CSR build
    hipMemsetAsync(counts, 0, (size_t)N * sizeof(int), stream);
    count_kernel<<<eBlocks, 256, 0, stream>>>(dst, counts, E);
    scan_kernel<<<1, SCAN_T, 0, stream>>>(counts, rowptr, N);
    copy_int_kernel<<<nBlocks, 256, 0, stream>>>(rowptr, cursor, N);
    reorder_kernel<<<eBlocks, 256, 0, stream>>>(src, dst, ew, cursor, comb, E);
    degw_kernel<<<nBlocks, 256, 0, stream>>>(rowptr, comb, dinv, N);

    // layer 1
    gemm1_kernel<<<gBlocks, 256, 0, stream>>>(x, W1, dinv, B1, N);
    pull_kernel<<<wBlocks, 256, 0, stream>>>(rowptr, comb, B1, B2, N);

    // layer 2 (input transform relu(dinv*acc1+b1) fused into GEMM2 staging)
    gemm2_kernel<<<gBlocks, 256, 0, stream>>>(B2, W2, dinv, b1, B1, N);
    pull_final_kernel<<<wBlocks, 256, 0, stream>>>(rowptr, comb, B1, dinv, b2, out, N);
}

// Round 5
// 543.951 us; speedup vs baseline: 1.3797x; 1.3797x over previous
//
#include <hip/hip_runtime.h>
#include <math.h>

// 2-layer GCN, N=100000, E=1.6M, DIN=256, HID=DOUT=64.
// L(x) = dinv ⊙ (A_w @ (dinv ⊙ (x@W))) + b, A_w incl. self-loops (w=1),
// dinv = rsqrt(deg_w + 1). g = dinv*(x@W) via register-tiled fp32 GEMM;
// CSR (dst-sorted) pull for scatter-add. Multi-block scan (was 162us 1-block).

#define GCN_DIN 256
#define GCN_HID 64
#define SCAN_B 1024   // elems per scan block

// ---------- CSR build ----------
__global__ void count_kernel(const int* __restrict__ dst, int* __restrict__ counts, int E) {
    int e = blockIdx.x * blockDim.x + threadIdx.x;
    if (e < E) atomicAdd(&counts[dst[e]], 1);
}

// pass 1: per-block reduce of counts
__global__ __launch_bounds__(SCAN_B) void scan_reduce_kernel(
    const int* __restrict__ counts, int* __restrict__ blockSums, int N)
{
    __shared__ int red[SCAN_B];
    int t = threadIdx.x;
    int i = blockIdx.x * SCAN_B + t;
    red[t] = (i < N) ? counts[i] : 0;
    __syncthreads();
    #pragma unroll
    for (int off = SCAN_B / 2; off > 0; off >>= 1) {
        if (t < off) red[t] += red[t + off];
        __syncthreads();
    }
    if (t == 0) blockSums[blockIdx.x] = red[0];
}

// pass 2: scan the (<=128) block sums; write exclusive offsets + rowptr[N]=total
__global__ __launch_bounds__(128) void scan_sums_kernel(
    const int* __restrict__ blockSums, int* __restrict__ blockOff,
    int* __restrict__ rowptr, int B, int N)
{
    __shared__ int s[128];
    int t = threadIdx.x;
    int v = (t < B) ? blockSums[t] : 0;
    s[t] = v;
    __syncthreads();
    #pragma unroll
    for (int off = 1; off < 128; off <<= 1) {
        int a = (t >= off) ? s[t - off] : 0;
        __syncthreads();
        s[t] += a;
        __syncthreads();
    }
    if (t < B) blockOff[t] = s[t] - v;         // exclusive
    if (t == B - 1) rowptr[N] = s[t];          // grand total
}

// pass 3: per-block inclusive scan + offset -> rowptr (exclusive) and cursor
__global__ __launch_bounds__(SCAN_B) void scan_final_kernel(
    const int* __restrict__ counts, const int* __restrict__ blockOff,
    int* __restrict__ rowptr, int* __restrict__ cursor, int N)
{
    __shared__ int s[SCAN_B];
    int t = threadIdx.x;
    int i = blockIdx.x * SCAN_B + t;
    int v = (i < N) ? counts[i] : 0;
    s[t] = v;
    __syncthreads();
    for (int off = 1; off < SCAN_B; off <<= 1) {
        int a = (t >= off) ? s[t - off] : 0;
        __syncthreads();
        s[t] += a;
        __syncthreads();
    }
    if (i < N) {
        int excl = blockOff[blockIdx.x] + s[t] - v;
        rowptr[i] = excl;
        cursor[i] = excl;
    }
}

__global__ void reorder_kernel(const int* __restrict__ src, const int* __restrict__ dst,
                               const float* __restrict__ ew, int* __restrict__ cursor,
                               int2* __restrict__ comb, int E) {
    int e = blockIdx.x * blockDim.x + threadIdx.x;
    if (e < E) {
        int d = dst[e];
        int pos = atomicAdd(&cursor[d], 1);
        comb[pos] = make_int2(src[e], __float_as_int(ew[e]));
    }
}

// dinv[n] = rsqrt(1 + sum of incoming ew)
__global__ void degw_kernel(const int* __restrict__ rowptr, const int2* __restrict__ comb,
                            float* __restrict__ dinv, int N) {
    int n = blockIdx.x * blockDim.x + threadIdx.x;
    if (n >= N) return;
    float s = 1.0f;
    int je = rowptr[n + 1];
    for (int j = rowptr[n]; j < je; ++j) s += __int_as_float(comb[j].y);
    dinv[n] = (s > 0.f) ? (1.0f / sqrtf(s)) : 0.f;
}

// ---------- GEMM1: g = dinv * (x @ W1), [N,256]x[256,64] ----------
__global__ __launch_bounds__(256) void gemm1_kernel(
    const float* __restrict__ x, const float* __restrict__ W,
    const float* __restrict__ dinv, float* __restrict__ g, int N)
{
    __shared__ float xs[32][68];
    __shared__ float ws[32][64];
    const int tid = threadIdx.x;
    const int tx = tid & 15;
    const int ty = tid >> 4;
    const int row0 = blockIdx.x * 64;

    float acc[4][4];
    #pragma unroll
    for (int i = 0; i < 4; ++i)
        #pragma unroll
        for (int j = 0; j < 4; ++j) acc[i][j] = 0.f;

    for (int k0 = 0; k0 < GCN_DIN; k0 += 32) {
        {
            int kc = tid & 7;
            int r  = tid >> 3;
            #pragma unroll
            for (int h = 0; h < 2; ++h) {
                int rr = r + 32 * h;
                int row = row0 + rr;
                float4 v = make_float4(0.f, 0.f, 0.f, 0.f);
                if (row < N) v = *(const float4*)&x[(size_t)row * GCN_DIN + k0 + kc * 4];
                xs[kc * 4 + 0][rr] = v.x;
                xs[kc * 4 + 1][rr] = v.y;
                xs[kc * 4 + 2][rr] = v.z;
                xs[kc * 4 + 3][rr] = v.w;
            }
        }
        {
            int c  = tid & 63;
            int kr = tid >> 6;
            #pragma unroll
            for (int h = 0; h < 8; ++h)
                ws[kr + 4 * h][c] = W[(size_t)(k0 + kr + 4 * h) * 64 + c];
        }
        __syncthreads();
        #pragma unroll
        for (int kk = 0; kk < 32; ++kk) {
            float4 a = *(const float4*)&xs[kk][ty * 4];
            float4 b = *(const float4*)&ws[kk][tx * 4];
            float av[4] = {a.x, a.y, a.z, a.w};
            float bv[4] = {b.x, b.y, b.z, b.w};
            #pragma unroll
            for (int i = 0; i < 4; ++i)
                #pragma unroll
                for (int j = 0; j < 4; ++j)
                    acc[i][j] = fmaf(av[i], bv[j], acc[i][j]);
        }
        __syncthreads();
    }
    #pragma unroll
    for (int i = 0; i < 4; ++i) {
        int row = row0 + ty * 4 + i;
        if (row < N) {
            float dv = dinv[row];
            float4 o = make_float4(dv * acc[i][0], dv * acc[i][1],
                                   dv * acc[i][2], dv * acc[i][3]);
            *(float4*)&g[(size_t)row * 64 + tx * 4] = o;
        }
    }
}

// ---------- GEMM2: g = dinv * (relu(dinv*acc1 + b1) @ W2), K=64 ----------
__global__ __launch_bounds__(256) void gemm2_kernel(
    const float* __restrict__ acc1, const float* __restrict__ W,
    const float* __restrict__ dinv, const float* __restrict__ b1,
    float* __restrict__ g, int N)
{
    __shared__ float xs[32][68];
    __shared__ float ws[32][64];
    const int tid = threadIdx.x;
    const int tx = tid & 15;
    const int ty = tid >> 4;
    const int row0 = blockIdx.x * 64;

    float acc[4][4];
    #pragma unroll
    for (int i = 0; i < 4; ++i)
        #pragma unroll
        for (int j = 0; j < 4; ++j) acc[i][j] = 0.f;

    for (int k0 = 0; k0 < GCN_HID; k0 += 32) {
        {
            int kc = tid & 7;
            int r  = tid >> 3;
            float4 bb = *(const float4*)&b1[k0 + kc * 4];
            #pragma unroll
            for (int h = 0; h < 2; ++h) {
                int rr = r + 32 * h;
                int row = row0 + rr;
                float4 v = make_float4(0.f, 0.f, 0.f, 0.f);
                if (row < N) {
                    float dv = dinv[row];
                    float4 hh = *(const float4*)&acc1[(size_t)row * 64 + k0 + kc * 4];
                    v.x = fmaxf(dv * hh.x + bb.x, 0.f);
                    v.y = fmaxf(dv * hh.y + bb.y, 0.f);
                    v.z = fmaxf(dv * hh.z + bb.z, 0.f);
                    v.w = fmaxf(dv * hh.w + bb.w, 0.f);
                }
                xs[kc * 4 + 0][rr] = v.x;
                xs[kc * 4 + 1][rr] = v.y;
                xs[kc * 4 + 2][rr] = v.z;
                xs[kc * 4 + 3][rr] = v.w;
            }
        }
        {
            int c  = tid & 63;
            int kr = tid >> 6;
            #pragma unroll
            for (int h = 0; h < 8; ++h)
                ws[kr + 4 * h][c] = W[(size_t)(k0 + kr + 4 * h) * 64 + c];
        }
        __syncthreads();
        #pragma unroll
        for (int kk = 0; kk < 32; ++kk) {
            float4 a = *(const float4*)&xs[kk][ty * 4];
            float4 b = *(const float4*)&ws[kk][tx * 4];
            float av[4] = {a.x, a.y, a.z, a.w};
            float bv[4] = {b.x, b.y, b.z, b.w};
            #pragma unroll
            for (int i = 0; i < 4; ++i)
                #pragma unroll
                for (int j = 0; j < 4; ++j)
                    acc[i][j] = fmaf(av[i], bv[j], acc[i][j]);
        }
        __syncthreads();
    }
    #pragma unroll
    for (int i = 0; i < 4; ++i) {
        int row = row0 + ty * 4 + i;
        if (row < N) {
            float dv = dinv[row];
            float4 o = make_float4(dv * acc[i][0], dv * acc[i][1],
                                   dv * acc[i][2], dv * acc[i][3]);
            *(float4*)&g[(size_t)row * 64 + tx * 4] = o;
        }
    }
}

// ---------- pull: out[n] = g[n] + sum_in ew * g[src]; wave per node ----------
__global__ __launch_bounds__(256) void pull_kernel(
    const int* __restrict__ rowptr, const int2* __restrict__ comb,
    const float* __restrict__ g, float* __restrict__ out, int N)
{
    int wid  = (blockIdx.x * blockDim.x + threadIdx.x) >> 6;
    int lane = threadIdx.x & 63;
    if (wid >= N) return;
    int jb = rowptr[wid], je = rowptr[wid + 1];
    float acc = g[(size_t)wid * 64 + lane];
    int j = jb;
    for (; j + 3 < je; j += 4) {
        int2 e0 = comb[j], e1 = comb[j + 1], e2 = comb[j + 2], e3 = comb[j + 3];
        float v0 = g[(size_t)e0.x * 64 + lane];
        float v1 = g[(size_t)e1.x * 64 + lane];
        float v2 = g[(size_t)e2.x * 64 + lane];
        float v3 = g[(size_t)e3.x * 64 + lane];
        acc = fmaf(__int_as_float(e0.y), v0, acc);
        acc = fmaf(__int_as_float(e1.y), v1, acc);
        acc = fmaf(__int_as_float(e2.y), v2, acc);
        acc = fmaf(__int_as_float(e3.y), v3, acc);
    }
    for (; j < je; ++j) {
        int2 e0 = comb[j];
        acc = fmaf(__int_as_float(e0.y), g[(size_t)e0.x * 64 + lane], acc);
    }
    out[(size_t)wid * 64 + lane] = acc;
}

// same, fused final epilogue: out = dinv[n]*acc + b2
__global__ __launch_bounds__(256) void pull_final_kernel(
    const int* __restrict__ rowptr, const int2* __restrict__ comb,
    const float* __restrict__ g, const float* __restrict__ dinv,
    const float* __restrict__ b2, float* __restrict__ out, int N)
{
    int wid  = (blockIdx.x * blockDim.x + threadIdx.x) >> 6;
    int lane = threadIdx.x & 63;
    if (wid >= N) return;
    int jb = rowptr[wid], je = rowptr[wid + 1];
    float acc = g[(size_t)wid * 64 + lane];
    int j = jb;
    for (; j + 3 < je; j += 4) {
        int2 e0 = comb[j], e1 = comb[j + 1], e2 = comb[j + 2], e3 = comb[j + 3];
        float v0 = g[(size_t)e0.x * 64 + lane];
        float v1 = g[(size_t)e1.x * 64 + lane];
        float v2 = g[(size_t)e2.x * 64 + lane];
        float v3 = g[(size_t)e3.x * 64 + lane];
        acc = fmaf(__int_as_float(e0.y), v0, acc);
        acc = fmaf(__int_as_float(e1.y), v1, acc);
        acc = fmaf(__int_as_float(e2.y), v2, acc);
        acc = fmaf(__int_as_float(e3.y), v3, acc);
    }
    for (; j < je; ++j) {
        int2 e0 = comb[j];
        acc = fmaf(__int_as_float(e0.y), g[(size_t)e0.x * 64 + lane], acc);
    }
    out[(size_t)wid * 64 + lane] = dinv[wid] * acc + b2[lane];
}

extern "C" void kernel_launch(void* const* d_in, const int* in_sizes, int n_in,
                              void* d_out, int out_size, void* d_ws, size_t ws_size,
                              hipStream_t stream) {
    const float* x  = (const float*)d_in[0];
    const int*   ei = (const int*)  d_in[1];
    const float* ew = (const float*)d_in[2];
    const float* W1 = (const float*)d_in[3];
    const float* b1 = (const float*)d_in[4];
    const float* W2 = (const float*)d_in[5];
    const float* b2 = (const float*)d_in[6];
    float* out = (float*)d_out;

    const int N = in_sizes[0] / GCN_DIN;   // 100000
    const int E = in_sizes[1] / 2;         // 1600000
    const int* src = ei;
    const int* dst = ei + E;

    // workspace: comb | B1 | B2 | dinv | counts | cursor | rowptr | blockSums | blockOff
    char* p = (char*)d_ws;
    int2*  comb   = (int2*)p;  p += (size_t)E * sizeof(int2);
    float* B1     = (float*)p; p += (size_t)N * 64 * sizeof(float);
    float* B2     = (float*)p; p += (size_t)N * 64 * sizeof(float);
    float* dinv   = (float*)p; p += (size_t)N * sizeof(float);
    int*   counts = (int*)p;   p += (size_t)N * sizeof(int);
    int*   cursor = (int*)p;   p += (size_t)N * sizeof(int);
    int*   rowptr = (int*)p;   p += (size_t)(N + 1) * sizeof(int);
    int*   blockSums = (int*)p; p += 128 * sizeof(int);
    int*   blockOff  = (int*)p; p += 128 * sizeof(int);

    const int eBlocks = (E + 255) / 256;
    const int gBlocks = (N + 63) / 64;
    const int wBlocks = (N + 3) / 4;
    const int sBlocks = (N + SCAN_B - 1) / SCAN_B;   // 98

    // CSR build
    hipMemsetAsync(counts, 0, (size_t)N * sizeof(int), stream);
    count_kernel<<<eBlocks, 256, 0, stream>>>(dst, counts, E);
    scan_reduce_kernel<<<sBlocks, SCAN_B, 0, stream>>>(counts, blockSums, N);
    scan_sums_kernel<<<1, 128, 0, stream>>>(blockSums, blockOff, rowptr, sBlocks, N);
    scan_final_kernel<<<sBlocks, SCAN_B, 0, stream>>>(counts, blockOff, rowptr, cursor, N);
    reorder_kernel<<<eBlocks, 256, 0, stream>>>(src, dst, ew, cursor, comb, E);
    degw_kernel<<<(N + 255) / 256, 256, 0, stream>>>(rowptr, comb, dinv, N);

    // layer 1
    gemm1_kernel<<<gBlocks, 256, 0, stream>>>(x, W1, dinv, B1, N);
    pull_kernel<<<wBlocks, 256, 0, stream>>>(rowptr, comb, B1, B2, N);

    // layer 2
    gemm2_kernel<<<gBlocks, 256, 0, stream>>>(B2, W2, dinv, b1, B1, N);
    pull_final_kernel<<<wBlocks, 256, 0, stream>>>(rowptr, comb, B1, dinv, b2, out, N);
}

// Round 8
// 497.111 us; speedup vs baseline: 1.5097x; 1.0942x over previous
//
#include <hip/hip_runtime.h>
#include <math.h>

// 2-layer GCN, N=100000, E=1.6M, DIN=256, HID=DOUT=64.
// L(x) = dinv ⊙ (A_w @ (dinv ⊙ (x@W))) + b, A_w incl. self-loops (w=1),
// dinv = rsqrt(deg_w + 1). g = dinv*(x@W) via register-tiled fp32 GEMM;
// CSR (dst-sorted) pull for scatter-add.
// R5: reorder_kernel had 100MB WRITE_SIZE (8x amplification from random 8B
// scatters). Replaced with bucketed partition (dst>>9, 196 buckets) + per-
// bucket LDS-cursor scatter: all writes are dense runs / L2-hot regions.

#define GCN_DIN 256
#define GCN_HID 64
#define SCAN_B 1024   // elems per scan block
#define PCHUNK 4096   // edges per partition block
#define NBMAX 256     // LDS histogram capacity (actual buckets = 196)

// ---------- CSR build ----------
__global__ void count_kernel(const int* __restrict__ dst, int* __restrict__ counts, int E) {
    int e = blockIdx.x * blockDim.x + threadIdx.x;
    if (e < E) atomicAdd(&counts[dst[e]], 1);
}

// pass 1: per-block reduce of counts
__global__ __launch_bounds__(SCAN_B) void scan_reduce_kernel(
    const int* __restrict__ counts, int* __restrict__ blockSums, int N)
{
    __shared__ int red[SCAN_B];
    int t = threadIdx.x;
    int i = blockIdx.x * SCAN_B + t;
    red[t] = (i < N) ? counts[i] : 0;
    __syncthreads();
    #pragma unroll
    for (int off = SCAN_B / 2; off > 0; off >>= 1) {
        if (t < off) red[t] += red[t + off];
        __syncthreads();
    }
    if (t == 0) blockSums[blockIdx.x] = red[0];
}

// pass 2: scan the (<=128) block sums; write exclusive offsets + rowptr[N]=total
__global__ __launch_bounds__(128) void scan_sums_kernel(
    const int* __restrict__ blockSums, int* __restrict__ blockOff,
    int* __restrict__ rowptr, int B, int N)
{
    __shared__ int s[128];
    int t = threadIdx.x;
    int v = (t < B) ? blockSums[t] : 0;
    s[t] = v;
    __syncthreads();
    #pragma unroll
    for (int off = 1; off < 128; off <<= 1) {
        int a = (t >= off) ? s[t - off] : 0;
        __syncthreads();
        s[t] += a;
        __syncthreads();
    }
    if (t < B) blockOff[t] = s[t] - v;         // exclusive
    if (t == B - 1) rowptr[N] = s[t];          // grand total
}

// pass 3: per-block inclusive scan + offset -> rowptr (exclusive)
__global__ __launch_bounds__(SCAN_B) void scan_final_kernel(
    const int* __restrict__ counts, const int* __restrict__ blockOff,
    int* __restrict__ rowptr, int N)
{
    __shared__ int s[SCAN_B];
    int t = threadIdx.x;
    int i = blockIdx.x * SCAN_B + t;
    int v = (i < N) ? counts[i] : 0;
    s[t] = v;
    __syncthreads();
    for (int off = 1; off < SCAN_B; off <<= 1) {
        int a = (t >= off) ? s[t - off] : 0;
        __syncthreads();
        s[t] += a;
        __syncthreads();
    }
    if (i < N) rowptr[i] = blockOff[blockIdx.x] + s[t] - v;
}

// bucket b covers nodes [b*512, (b+1)*512); its comb/tmp range starts at rowptr[b*512]
__global__ void bcur_init_kernel(const int* __restrict__ rowptr, int* __restrict__ bucketCursor,
                                 int NB, int N) {
    int b = blockIdx.x * blockDim.x + threadIdx.x;
    if (b < NB) {
        int node = b << 9;
        bucketCursor[b] = rowptr[node < N ? node : N];
    }
}

// phase A: partition edges into dst-range buckets; writes are dense per-(block,bucket) runs
__global__ __launch_bounds__(256) void partition_kernel(
    const int* __restrict__ src, const int* __restrict__ dst, const float* __restrict__ ew,
    int* __restrict__ bucketCursor, int2* __restrict__ tmp, int E)
{
    __shared__ int hcount[NBMAX];
    __shared__ int hbase[NBMAX];
    __shared__ int hoff[NBMAX];
    const int tid = threadIdx.x;
    const int b0 = blockIdx.x * PCHUNK;
    const int bend = (b0 + PCHUNK < E) ? (b0 + PCHUNK) : E;

    for (int i = tid; i < NBMAX; i += 256) { hcount[i] = 0; hoff[i] = 0; }
    __syncthreads();
    for (int e = b0 + tid; e < bend; e += 256)
        atomicAdd(&hcount[dst[e] >> 9], 1);
    __syncthreads();
    for (int i = tid; i < NBMAX; i += 256)
        if (hcount[i] > 0) hbase[i] = atomicAdd(&bucketCursor[i], hcount[i]);
    __syncthreads();
    for (int e = b0 + tid; e < bend; e += 256) {
        int d = dst[e];
        int b = d >> 9;
        int off = atomicAdd(&hoff[b], 1);
        int key = ((d & 511) << 17) | src[e];       // src < 2^17, local_dst < 2^9
        tmp[hbase[b] + off] = make_int2(key, __float_as_int(ew[e]));
    }
}

// phase B: per-bucket scatter into final CSR slots (comb region is a hot ~64KB window)
__global__ __launch_bounds__(256) void bucket_scatter_kernel(
    const int* __restrict__ rowptr, const int2* __restrict__ tmp,
    int2* __restrict__ comb, int N)
{
    __shared__ int cur[512];
    const int tid = threadIdx.x;
    const int base = blockIdx.x << 9;
    const int nn = (base + 512 < N) ? 512 : (N - base);
    for (int i = tid; i < nn; i += 256) cur[i] = rowptr[base + i];
    __syncthreads();
    const int jb = rowptr[base];
    const int je = rowptr[base + nn];
    for (int j = jb + tid; j < je; j += 256) {
        int2 t = tmp[j];
        int local = t.x >> 17;
        int s = t.x & 0x1FFFF;
        int pos = atomicAdd(&cur[local], 1);
        comb[pos] = make_int2(s, t.y);
    }
}

// dinv[n] = rsqrt(1 + sum of incoming ew)
__global__ void degw_kernel(const int* __restrict__ rowptr, const int2* __restrict__ comb,
                            float* __restrict__ dinv, int N) {
    int n = blockIdx.x * blockDim.x + threadIdx.x;
    if (n >= N) return;
    float s = 1.0f;
    int je = rowptr[n + 1];
    for (int j = rowptr[n]; j < je; ++j) s += __int_as_float(comb[j].y);
    dinv[n] = (s > 0.f) ? (1.0f / sqrtf(s)) : 0.f;
}

// ---------- GEMM1: g = dinv * (x @ W1), [N,256]x[256,64] ----------
__global__ __launch_bounds__(256) void gemm1_kernel(
    const float* __restrict__ x, const float* __restrict__ W,
    const float* __restrict__ dinv, float* __restrict__ g, int N)
{
    __shared__ float xs[32][68];
    __shared__ float ws[32][64];
    const int tid = threadIdx.x;
    const int tx = tid & 15;
    const int ty = tid >> 4;
    const int row0 = blockIdx.x * 64;

    float acc[4][4];
    #pragma unroll
    for (int i = 0; i < 4; ++i)
        #pragma unroll
        for (int j = 0; j < 4; ++j) acc[i][j] = 0.f;

    for (int k0 = 0; k0 < GCN_DIN; k0 += 32) {
        {
            int kc = tid & 7;
            int r  = tid >> 3;
            #pragma unroll
            for (int h = 0; h < 2; ++h) {
                int rr = r + 32 * h;
                int row = row0 + rr;
                float4 v = make_float4(0.f, 0.f, 0.f, 0.f);
                if (row < N) v = *(const float4*)&x[(size_t)row * GCN_DIN + k0 + kc * 4];
                xs[kc * 4 + 0][rr] = v.x;
                xs[kc * 4 + 1][rr] = v.y;
                xs[kc * 4 + 2][rr] = v.z;
                xs[kc * 4 + 3][rr] = v.w;
            }
        }
        {
            int c  = tid & 63;
            int kr = tid >> 6;
            #pragma unroll
            for (int h = 0; h < 8; ++h)
                ws[kr + 4 * h][c] = W[(size_t)(k0 + kr + 4 * h) * 64 + c];
        }
        __syncthreads();
        #pragma unroll
        for (int kk = 0; kk < 32; ++kk) {
            float4 a = *(const float4*)&xs[kk][ty * 4];
            float4 b = *(const float4*)&ws[kk][tx * 4];
            float av[4] = {a.x, a.y, a.z, a.w};
            float bv[4] = {b.x, b.y, b.z, b.w};
            #pragma unroll
            for (int i = 0; i < 4; ++i)
                #pragma unroll
                for (int j = 0; j < 4; ++j)
                    acc[i][j] = fmaf(av[i], bv[j], acc[i][j]);
        }
        __syncthreads();
    }
    #pragma unroll
    for (int i = 0; i < 4; ++i) {
        int row = row0 + ty * 4 + i;
        if (row < N) {
            float dv = dinv[row];
            float4 o = make_float4(dv * acc[i][0], dv * acc[i][1],
                                   dv * acc[i][2], dv * acc[i][3]);
            *(float4*)&g[(size_t)row * 64 + tx * 4] = o;
        }
    }
}

// ---------- GEMM2: g = dinv * (relu(dinv*acc1 + b1) @ W2), K=64 ----------
__global__ __launch_bounds__(256) void gemm2_kernel(
    const float* __restrict__ acc1, const float* __restrict__ W,
    const float* __restrict__ dinv, const float* __restrict__ b1,
    float* __restrict__ g, int N)
{
    __shared__ float xs[32][68];
    __shared__ float ws[32][64];
    const int tid = threadIdx.x;
    const int tx = tid & 15;
    const int ty = tid >> 4;
    const int row0 = blockIdx.x * 64;

    float acc[4][4];
    #pragma unroll
    for (int i = 0; i < 4; ++i)
        #pragma unroll
        for (int j = 0; j < 4; ++j) acc[i][j] = 0.f;

    for (int k0 = 0; k0 < GCN_HID; k0 += 32) {
        {
            int kc = tid & 7;
            int r  = tid >> 3;
            float4 bb = *(const float4*)&b1[k0 + kc * 4];
            #pragma unroll
            for (int h = 0; h < 2; ++h) {
                int rr = r + 32 * h;
                int row = row0 + rr;
                float4 v = make_float4(0.f, 0.f, 0.f, 0.f);
                if (row < N) {
                    float dv = dinv[row];
                    float4 hh = *(const float4*)&acc1[(size_t)row * 64 + k0 + kc * 4];
                    v.x = fmaxf(dv * hh.x + bb.x, 0.f);
                    v.y = fmaxf(dv * hh.y + bb.y, 0.f);
                    v.z = fmaxf(dv * hh.z + bb.z, 0.f);
                    v.w = fmaxf(dv * hh.w + bb.w, 0.f);
                }
                xs[kc * 4 + 0][rr] = v.x;
                xs[kc * 4 + 1][rr] = v.y;
                xs[kc * 4 + 2][rr] = v.z;
                xs[kc * 4 + 3][rr] = v.w;
            }
        }
        {
            int c  = tid & 63;
            int kr = tid >> 6;
            #pragma unroll
            for (int h = 0; h < 8; ++h)
                ws[kr + 4 * h][c] = W[(size_t)(k0 + kr + 4 * h) * 64 + c];
        }
        __syncthreads();
        #pragma unroll
        for (int kk = 0; kk < 32; ++kk) {
            float4 a = *(const float4*)&xs[kk][ty * 4];
            float4 b = *(const float4*)&ws[kk][tx * 4];
            float av[4] = {a.x, a.y, a.z, a.w};
            float bv[4] = {b.x, b.y, b.z, b.w};
            #pragma unroll
            for (int i = 0; i < 4; ++i)
                #pragma unroll
                for (int j = 0; j < 4; ++j)
                    acc[i][j] = fmaf(av[i], bv[j], acc[i][j]);
        }
        __syncthreads();
    }
    #pragma unroll
    for (int i = 0; i < 4; ++i) {
        int row = row0 + ty * 4 + i;
        if (row < N) {
            float dv = dinv[row];
            float4 o = make_float4(dv * acc[i][0], dv * acc[i][1],
                                   dv * acc[i][2], dv * acc[i][3]);
            *(float4*)&g[(size_t)row * 64 + tx * 4] = o;
        }
    }
}

// ---------- pull: out[n] = g[n] + sum_in ew * g[src]; wave per node ----------
__global__ __launch_bounds__(256) void pull_kernel(
    const int* __restrict__ rowptr, const int2* __restrict__ comb,
    const float* __restrict__ g, float* __restrict__ out, int N)
{
    int wid  = (blockIdx.x * blockDim.x + threadIdx.x) >> 6;
    int lane = threadIdx.x & 63;
    if (wid >= N) return;
    int jb = rowptr[wid], je = rowptr[wid + 1];
    float acc = g[(size_t)wid * 64 + lane];
    int j = jb;
    for (; j + 3 < je; j += 4) {
        int2 e0 = comb[j], e1 = comb[j + 1], e2 = comb[j + 2], e3 = comb[j + 3];
        float v0 = g[(size_t)e0.x * 64 + lane];
        float v1 = g[(size_t)e1.x * 64 + lane];
        float v2 = g[(size_t)e2.x * 64 + lane];
        float v3 = g[(size_t)e3.x * 64 + lane];
        acc = fmaf(__int_as_float(e0.y), v0, acc);
        acc = fmaf(__int_as_float(e1.y), v1, acc);
        acc = fmaf(__int_as_float(e2.y), v2, acc);
        acc = fmaf(__int_as_float(e3.y), v3, acc);
    }
    for (; j < je; ++j) {
        int2 e0 = comb[j];
        acc = fmaf(__int_as_float(e0.y), g[(size_t)e0.x * 64 + lane], acc);
    }
    out[(size_t)wid * 64 + lane] = acc;
}

// same, fused final epilogue: out = dinv[n]*acc + b2
__global__ __launch_bounds__(256) void pull_final_kernel(
    const int* __restrict__ rowptr, const int2* __restrict__ comb,
    const float* __restrict__ g, const float* __restrict__ dinv,
    const float* __restrict__ b2, float* __restrict__ out, int N)
{
    int wid  = (blockIdx.x * blockDim.x + threadIdx.x) >> 6;
    int lane = threadIdx.x & 63;
    if (wid >= N) return;
    int jb = rowptr[wid], je = rowptr[wid + 1];
    float acc = g[(size_t)wid * 64 + lane];
    int j = jb;
    for (; j + 3 < je; j += 4) {
        int2 e0 = comb[j], e1 = comb[j + 1], e2 = comb[j + 2], e3 = comb[j + 3];
        float v0 = g[(size_t)e0.x * 64 + lane];
        float v1 = g[(size_t)e1.x * 64 + lane];
        float v2 = g[(size_t)e2.x * 64 + lane];
        float v3 = g[(size_t)e3.x * 64 + lane];
        acc = fmaf(__int_as_float(e0.y), v0, acc);
        acc = fmaf(__int_as_float(e1.y), v1, acc);
        acc = fmaf(__int_as_float(e2.y), v2, acc);
        acc = fmaf(__int_as_float(e3.y), v3, acc);
    }
    for (; j < je; ++j) {
        int2 e0 = comb[j];
        acc = fmaf(__int_as_float(e0.y), g[(size_t)e0.x * 64 + lane], acc);
    }
    out[(size_t)wid * 64 + lane] = dinv[wid] * acc + b2[lane];
}

extern "C" void kernel_launch(void* const* d_in, const int* in_sizes, int n_in,
                              void* d_out, int out_size, void* d_ws, size_t ws_size,
                              hipStream_t stream) {
    const float* x  = (const float*)d_in[0];
    const int*   ei = (const int*)  d_in[1];
    const float* ew = (const float*)d_in[2];
    const float* W1 = (const float*)d_in[3];
    const float* b1 = (const float*)d_in[4];
    const float* W2 = (const float*)d_in[5];
    const float* b2 = (const float*)d_in[6];
    float* out = (float*)d_out;

    const int N = in_sizes[0] / GCN_DIN;   // 100000
    const int E = in_sizes[1] / 2;         // 1600000
    const int* src = ei;
    const int* dst = ei + E;
    const int NB = (N + 511) >> 9;         // 196 buckets

    // workspace: comb | B1 | B2 | dinv | counts | rowptr | blockSums | blockOff | bucketCursor
    char* p = (char*)d_ws;
    int2*  comb   = (int2*)p;  p += (size_t)E * sizeof(int2);
    float* B1     = (float*)p; p += (size_t)N * 64 * sizeof(float);
    float* B2     = (float*)p; p += (size_t)N * 64 * sizeof(float);
    float* dinv   = (float*)p; p += (size_t)N * sizeof(float);
    int*   counts = (int*)p;   p += (size_t)N * sizeof(int);
    int*   rowptr = (int*)p;   p += (size_t)(N + 1) * sizeof(int);
    int*   blockSums = (int*)p; p += 128 * sizeof(int);
    int*   blockOff  = (int*)p; p += 128 * sizeof(int);
    int*   bucketCursor = (int*)p; p += NBMAX * sizeof(int);
    int2*  tmp = (int2*)B1;    // B1 is dead until gemm1; reuse as partition buffer

    const int eBlocks = (E + 255) / 256;
    const int gBlocks = (N + 63) / 64;
    const int wBlocks = (N + 3) / 4;
    const int sBlocks = (N + SCAN_B - 1) / SCAN_B;   // 98
    const int pBlocks = (E + PCHUNK - 1) / PCHUNK;   // 391

    // CSR build
    hipMemsetAsync(counts, 0, (size_t)N * sizeof(int), stream);
    count_kernel<<<eBlocks, 256, 0, stream>>>(dst, counts, E);
    scan_reduce_kernel<<<sBlocks, SCAN_B, 0, stream>>>(counts, blockSums, N);
    scan_sums_kernel<<<1, 128, 0, stream>>>(blockSums, blockOff, rowptr, sBlocks, N);
    scan_final_kernel<<<sBlocks, SCAN_B, 0, stream>>>(counts, blockOff, rowptr, N);
    bcur_init_kernel<<<1, 256, 0, stream>>>(rowptr, bucketCursor, NB, N);
    partition_kernel<<<pBlocks, 256, 0, stream>>>(src, dst, ew, bucketCursor, tmp, E);
    bucket_scatter_kernel<<<NB, 256, 0, stream>>>(rowptr, tmp, comb, N);
    degw_kernel<<<(N + 255) / 256, 256, 0, stream>>>(rowptr, comb, dinv, N);

    // layer 1
    gemm1_kernel<<<gBlocks, 256, 0, stream>>>(x, W1, dinv, B1, N);
    pull_kernel<<<wBlocks, 256, 0, stream>>>(rowptr, comb, B1, B2, N);

    // layer 2
    gemm2_kernel<<<gBlocks, 256, 0, stream>>>(B2, W2, dinv, b1, B1, N);
    pull_final_kernel<<<wBlocks, 256, 0, stream>>>(rowptr, comb, B1, dinv, b2, out, N);
}

// Round 9
// 461.943 us; speedup vs baseline: 1.6247x; 1.0761x over previous
//
#include <hip/hip_runtime.h>
#include <math.h>

// 2-layer GCN, N=100000, E=1.6M, DIN=256, HID=DOUT=64.
// L(x) = dinv ⊙ (A_w @ (dinv ⊙ (x@W))) + b, A_w incl self-loops, dinv=rsqrt(deg+1).
// R5: bucketed partition kills reorder's 8x write amplification (125->~40us).
// R8: pulls measured at 77.5us, FETCH 193MB = 8 XCD x 22MB L2 duplication of the
//     25.6MB g-table (random graph, structural). CSR build collapsed into
//     bucket-count + bucket-scan + fused per-bucket finalize (rowptr+dinv+comb
//     from L2-hot tmp); pull unroll 8 with dual accumulators.

#define GCN_DIN 256
#define GCN_HID 64
#define PCHUNK 4096   // edges per partition block
#define NBMAX 256     // bucket capacity (actual = ceil(N/512) = 196)

// ---------- A: per-bucket edge histogram ----------
__global__ __launch_bounds__(256) void bucket_count_kernel(
    const int* __restrict__ dst, int* __restrict__ bucketCount, int E)
{
    __shared__ int h[NBMAX];
    for (int i = threadIdx.x; i < NBMAX; i += 256) h[i] = 0;
    __syncthreads();
    int stride = gridDim.x * 256;
    for (int e = blockIdx.x * 256 + threadIdx.x; e < E; e += stride)
        atomicAdd(&h[dst[e] >> 9], 1);
    __syncthreads();
    for (int i = threadIdx.x; i < NBMAX; i += 256)
        if (h[i]) atomicAdd(&bucketCount[i], h[i]);
}

// ---------- B: scan 196 bucket counts -> bucketBase, init cursors ----------
__global__ __launch_bounds__(NBMAX) void bucket_scan_kernel(
    const int* __restrict__ bucketCount, int* __restrict__ bucketBase,
    int* __restrict__ bucketCursor, int NB)
{
    __shared__ int s[NBMAX];
    int t = threadIdx.x;
    int v = (t < NB) ? bucketCount[t] : 0;
    s[t] = v;
    __syncthreads();
    for (int off = 1; off < NBMAX; off <<= 1) {
        int a = (t >= off) ? s[t - off] : 0;
        __syncthreads();
        s[t] += a;
        __syncthreads();
    }
    if (t < NB) { int ex = s[t] - v; bucketBase[t] = ex; bucketCursor[t] = ex; }
    if (t == NB - 1) bucketBase[NB] = s[t];
}

// ---------- C: partition edges into dst-range buckets (dense runs) ----------
__global__ __launch_bounds__(256) void partition_kernel(
    const int* __restrict__ src, const int* __restrict__ dst, const float* __restrict__ ew,
    int* __restrict__ bucketCursor, int2* __restrict__ tmp, int E)
{
    __shared__ int hcount[NBMAX];
    __shared__ int hbase[NBMAX];
    __shared__ int hoff[NBMAX];
    const int tid = threadIdx.x;
    const int b0 = blockIdx.x * PCHUNK;
    const int bend = (b0 + PCHUNK < E) ? (b0 + PCHUNK) : E;

    for (int i = tid; i < NBMAX; i += 256) { hcount[i] = 0; hoff[i] = 0; }
    __syncthreads();
    for (int e = b0 + tid; e < bend; e += 256)
        atomicAdd(&hcount[dst[e] >> 9], 1);
    __syncthreads();
    for (int i = tid; i < NBMAX; i += 256)
        if (hcount[i] > 0) hbase[i] = atomicAdd(&bucketCursor[i], hcount[i]);
    __syncthreads();
    for (int e = b0 + tid; e < bend; e += 256) {
        int d = dst[e];
        int b = d >> 9;
        int off = atomicAdd(&hoff[b], 1);
        int key = ((d & 511) << 17) | src[e];     // src < 2^17, local_dst < 2^9
        tmp[hbase[b] + off] = make_int2(key, __float_as_int(ew[e]));
    }
}

// ---------- D: per-bucket finalize: counts+ewsum -> rowptr+dinv, scatter comb ----------
__global__ __launch_bounds__(256) void bucket_finalize_kernel(
    const int* __restrict__ bucketBase, const int2* __restrict__ tmp,
    int2* __restrict__ comb, int* __restrict__ rowptr, float* __restrict__ dinv,
    int N, int NB)
{
    __shared__ int   cnt[512];
    __shared__ float ews[512];
    __shared__ int   sc[512];
    __shared__ int   cur[512];
    const int tid = threadIdx.x;
    const int b = blockIdx.x;
    const int base = b << 9;
    const int nn = (base + 512 < N) ? 512 : (N - base);
    for (int i = tid; i < 512; i += 256) { cnt[i] = 0; ews[i] = 0.f; }
    __syncthreads();
    const int jb = bucketBase[b], je = bucketBase[b + 1];
    for (int j = jb + tid; j < je; j += 256) {
        int2 t = tmp[j];
        int l = t.x >> 17;
        atomicAdd(&cnt[l], 1);
        atomicAdd(&ews[l], __int_as_float(t.y));
    }
    __syncthreads();
    // inclusive scan of cnt (512 elems, 256 threads, pre-read + barrier)
    for (int i = tid; i < 512; i += 256) sc[i] = cnt[i];
    __syncthreads();
    for (int off = 1; off < 512; off <<= 1) {
        int i0 = tid, i1 = tid + 256;
        int v0 = (i0 >= off) ? sc[i0 - off] : 0;
        int v1 = (i1 >= off) ? sc[i1 - off] : 0;
        __syncthreads();
        sc[i0] += v0; sc[i1] += v1;
        __syncthreads();
    }
    for (int i = tid; i < 512; i += 256) cur[i] = sc[i] - cnt[i];   // exclusive
    __syncthreads();
    for (int i = tid; i < nn; i += 256) {
        rowptr[base + i] = jb + cur[i];
        float s = 1.0f + ews[i];
        dinv[base + i] = (s > 0.f) ? (1.0f / sqrtf(s)) : 0.f;
    }
    if (b == NB - 1 && tid == 0) rowptr[N] = je;
    __syncthreads();
    for (int j = jb + tid; j < je; j += 256) {
        int2 t = tmp[j];
        int l = t.x >> 17;
        int pos = jb + atomicAdd(&cur[l], 1);
        comb[pos] = make_int2(t.x & 0x1FFFF, t.y);
    }
}

// ---------- GEMM1: g = dinv * (x @ W1), [N,256]x[256,64] ----------
__global__ __launch_bounds__(256) void gemm1_kernel(
    const float* __restrict__ x, const float* __restrict__ W,
    const float* __restrict__ dinv, float* __restrict__ g, int N)
{
    __shared__ float xs[32][68];
    __shared__ float ws[32][64];
    const int tid = threadIdx.x;
    const int tx = tid & 15;
    const int ty = tid >> 4;
    const int row0 = blockIdx.x * 64;

    float acc[4][4];
    #pragma unroll
    for (int i = 0; i < 4; ++i)
        #pragma unroll
        for (int j = 0; j < 4; ++j) acc[i][j] = 0.f;

    for (int k0 = 0; k0 < GCN_DIN; k0 += 32) {
        {
            int kc = tid & 7;
            int r  = tid >> 3;
            #pragma unroll
            for (int h = 0; h < 2; ++h) {
                int rr = r + 32 * h;
                int row = row0 + rr;
                float4 v = make_float4(0.f, 0.f, 0.f, 0.f);
                if (row < N) v = *(const float4*)&x[(size_t)row * GCN_DIN + k0 + kc * 4];
                xs[kc * 4 + 0][rr] = v.x;
                xs[kc * 4 + 1][rr] = v.y;
                xs[kc * 4 + 2][rr] = v.z;
                xs[kc * 4 + 3][rr] = v.w;
            }
        }
        {
            int c  = tid & 63;
            int kr = tid >> 6;
            #pragma unroll
            for (int h = 0; h < 8; ++h)
                ws[kr + 4 * h][c] = W[(size_t)(k0 + kr + 4 * h) * 64 + c];
        }
        __syncthreads();
        #pragma unroll
        for (int kk = 0; kk < 32; ++kk) {
            float4 a = *(const float4*)&xs[kk][ty * 4];
            float4 b = *(const float4*)&ws[kk][tx * 4];
            float av[4] = {a.x, a.y, a.z, a.w};
            float bv[4] = {b.x, b.y, b.z, b.w};
            #pragma unroll
            for (int i = 0; i < 4; ++i)
                #pragma unroll
                for (int j = 0; j < 4; ++j)
                    acc[i][j] = fmaf(av[i], bv[j], acc[i][j]);
        }
        __syncthreads();
    }
    #pragma unroll
    for (int i = 0; i < 4; ++i) {
        int row = row0 + ty * 4 + i;
        if (row < N) {
            float dv = dinv[row];
            float4 o = make_float4(dv * acc[i][0], dv * acc[i][1],
                                   dv * acc[i][2], dv * acc[i][3]);
            *(float4*)&g[(size_t)row * 64 + tx * 4] = o;
        }
    }
}

// ---------- GEMM2: g = dinv * (relu(dinv*acc1 + b1) @ W2), K=64 ----------
__global__ __launch_bounds__(256) void gemm2_kernel(
    const float* __restrict__ acc1, const float* __restrict__ W,
    const float* __restrict__ dinv, const float* __restrict__ b1,
    float* __restrict__ g, int N)
{
    __shared__ float xs[32][68];
    __shared__ float ws[32][64];
    const int tid = threadIdx.x;
    const int tx = tid & 15;
    const int ty = tid >> 4;
    const int row0 = blockIdx.x * 64;

    float acc[4][4];
    #pragma unroll
    for (int i = 0; i < 4; ++i)
        #pragma unroll
        for (int j = 0; j < 4; ++j) acc[i][j] = 0.f;

    for (int k0 = 0; k0 < GCN_HID; k0 += 32) {
        {
            int kc = tid & 7;
            int r  = tid >> 3;
            float4 bb = *(const float4*)&b1[k0 + kc * 4];
            #pragma unroll
            for (int h = 0; h < 2; ++h) {
                int rr = r + 32 * h;
                int row = row0 + rr;
                float4 v = make_float4(0.f, 0.f, 0.f, 0.f);
                if (row < N) {
                    float dv = dinv[row];
                    float4 hh = *(const float4*)&acc1[(size_t)row * 64 + k0 + kc * 4];
                    v.x = fmaxf(dv * hh.x + bb.x, 0.f);
                    v.y = fmaxf(dv * hh.y + bb.y, 0.f);
                    v.z = fmaxf(dv * hh.z + bb.z, 0.f);
                    v.w = fmaxf(dv * hh.w + bb.w, 0.f);
                }
                xs[kc * 4 + 0][rr] = v.x;
                xs[kc * 4 + 1][rr] = v.y;
                xs[kc * 4 + 2][rr] = v.z;
                xs[kc * 4 + 3][rr] = v.w;
            }
        }
        {
            int c  = tid & 63;
            int kr = tid >> 6;
            #pragma unroll
            for (int h = 0; h < 8; ++h)
                ws[kr + 4 * h][c] = W[(size_t)(k0 + kr + 4 * h) * 64 + c];
        }
        __syncthreads();
        #pragma unroll
        for (int kk = 0; kk < 32; ++kk) {
            float4 a = *(const float4*)&xs[kk][ty * 4];
            float4 b = *(const float4*)&ws[kk][tx * 4];
            float av[4] = {a.x, a.y, a.z, a.w};
            float bv[4] = {b.x, b.y, b.z, b.w};
            #pragma unroll
            for (int i = 0; i < 4; ++i)
                #pragma unroll
                for (int j = 0; j < 4; ++j)
                    acc[i][j] = fmaf(av[i], bv[j], acc[i][j]);
        }
        __syncthreads();
    }
    #pragma unroll
    for (int i = 0; i < 4; ++i) {
        int row = row0 + ty * 4 + i;
        if (row < N) {
            float dv = dinv[row];
            float4 o = make_float4(dv * acc[i][0], dv * acc[i][1],
                                   dv * acc[i][2], dv * acc[i][3]);
            *(float4*)&g[(size_t)row * 64 + tx * 4] = o;
        }
    }
}

// ---------- pull: out[n] = g[n] + sum_in ew * g[src]; wave per node, 8-deep ----------
__global__ __launch_bounds__(256) void pull_kernel(
    const int* __restrict__ rowptr, const int2* __restrict__ comb,
    const float* __restrict__ g, float* __restrict__ out, int N)
{
    int wid  = (blockIdx.x * blockDim.x + threadIdx.x) >> 6;
    int lane = threadIdx.x & 63;
    if (wid >= N) return;
    int jb = rowptr[wid], je = rowptr[wid + 1];
    float acc0 = g[(size_t)wid * 64 + lane];
    float acc1 = 0.f;
    int j = jb;
    for (; j + 7 < je; j += 8) {
        int2 e0 = comb[j],     e1 = comb[j + 1], e2 = comb[j + 2], e3 = comb[j + 3];
        int2 e4 = comb[j + 4], e5 = comb[j + 5], e6 = comb[j + 6], e7 = comb[j + 7];
        float v0 = g[(size_t)e0.x * 64 + lane];
        float v1 = g[(size_t)e1.x * 64 + lane];
        float v2 = g[(size_t)e2.x * 64 + lane];
        float v3 = g[(size_t)e3.x * 64 + lane];
        float v4 = g[(size_t)e4.x * 64 + lane];
        float v5 = g[(size_t)e5.x * 64 + lane];
        float v6 = g[(size_t)e6.x * 64 + lane];
        float v7 = g[(size_t)e7.x * 64 + lane];
        acc0 = fmaf(__int_as_float(e0.y), v0, acc0);
        acc1 = fmaf(__int_as_float(e1.y), v1, acc1);
        acc0 = fmaf(__int_as_float(e2.y), v2, acc0);
        acc1 = fmaf(__int_as_float(e3.y), v3, acc1);
        acc0 = fmaf(__int_as_float(e4.y), v4, acc0);
        acc1 = fmaf(__int_as_float(e5.y), v5, acc1);
        acc0 = fmaf(__int_as_float(e6.y), v6, acc0);
        acc1 = fmaf(__int_as_float(e7.y), v7, acc1);
    }
    for (; j < je; ++j) {
        int2 e0 = comb[j];
        acc0 = fmaf(__int_as_float(e0.y), g[(size_t)e0.x * 64 + lane], acc0);
    }
    out[(size_t)wid * 64 + lane] = acc0 + acc1;
}

// same, fused final epilogue: out = dinv[n]*acc + b2
__global__ __launch_bounds__(256) void pull_final_kernel(
    const int* __restrict__ rowptr, const int2* __restrict__ comb,
    const float* __restrict__ g, const float* __restrict__ dinv,
    const float* __restrict__ b2, float* __restrict__ out, int N)
{
    int wid  = (blockIdx.x * blockDim.x + threadIdx.x) >> 6;
    int lane = threadIdx.x & 63;
    if (wid >= N) return;
    int jb = rowptr[wid], je = rowptr[wid + 1];
    float acc0 = g[(size_t)wid * 64 + lane];
    float acc1 = 0.f;
    int j = jb;
    for (; j + 7 < je; j += 8) {
        int2 e0 = comb[j],     e1 = comb[j + 1], e2 = comb[j + 2], e3 = comb[j + 3];
        int2 e4 = comb[j + 4], e5 = comb[j + 5], e6 = comb[j + 6], e7 = comb[j + 7];
        float v0 = g[(size_t)e0.x * 64 + lane];
        float v1 = g[(size_t)e1.x * 64 + lane];
        float v2 = g[(size_t)e2.x * 64 + lane];
        float v3 = g[(size_t)e3.x * 64 + lane];
        float v4 = g[(size_t)e4.x * 64 + lane];
        float v5 = g[(size_t)e5.x * 64 + lane];
        float v6 = g[(size_t)e6.x * 64 + lane];
        float v7 = g[(size_t)e7.x * 64 + lane];
        acc0 = fmaf(__int_as_float(e0.y), v0, acc0);
        acc1 = fmaf(__int_as_float(e1.y), v1, acc1);
        acc0 = fmaf(__int_as_float(e2.y), v2, acc0);
        acc1 = fmaf(__int_as_float(e3.y), v3, acc1);
        acc0 = fmaf(__int_as_float(e4.y), v4, acc0);
        acc1 = fmaf(__int_as_float(e5.y), v5, acc1);
        acc0 = fmaf(__int_as_float(e6.y), v6, acc0);
        acc1 = fmaf(__int_as_float(e7.y), v7, acc1);
    }
    for (; j < je; ++j) {
        int2 e0 = comb[j];
        acc0 = fmaf(__int_as_float(e0.y), g[(size_t)e0.x * 64 + lane], acc0);
    }
    out[(size_t)wid * 64 + lane] = dinv[wid] * (acc0 + acc1) + b2[lane];
}

extern "C" void kernel_launch(void* const* d_in, const int* in_sizes, int n_in,
                              void* d_out, int out_size, void* d_ws, size_t ws_size,
                              hipStream_t stream) {
    const float* x  = (const float*)d_in[0];
    const int*   ei = (const int*)  d_in[1];
    const float* ew = (const float*)d_in[2];
    const float* W1 = (const float*)d_in[3];
    const float* b1 = (const float*)d_in[4];
    const float* W2 = (const float*)d_in[5];
    const float* b2 = (const float*)d_in[6];
    float* out = (float*)d_out;

    const int N = in_sizes[0] / GCN_DIN;   // 100000
    const int E = in_sizes[1] / 2;         // 1600000
    const int* src = ei;
    const int* dst = ei + E;
    const int NB = (N + 511) >> 9;         // 196 buckets

    // workspace: comb | B1 | B2 | dinv | rowptr | bucketCount | bucketBase | bucketCursor
    char* p = (char*)d_ws;
    int2*  comb   = (int2*)p;  p += (size_t)E * sizeof(int2);
    float* B1     = (float*)p; p += (size_t)N * 64 * sizeof(float);
    float* B2     = (float*)p; p += (size_t)N * 64 * sizeof(float);
    float* dinv   = (float*)p; p += (size_t)N * sizeof(float);
    int*   rowptr = (int*)p;   p += (size_t)(N + 1) * sizeof(int);
    int*   bucketCount  = (int*)p; p += NBMAX * sizeof(int);
    int*   bucketBase   = (int*)p; p += (NBMAX + 1) * sizeof(int);
    int*   bucketCursor = (int*)p; p += NBMAX * sizeof(int);
    int2*  tmp = (int2*)B1;    // B1 dead until gemm1; reuse as partition buffer

    const int gBlocks = (N + 63) / 64;
    const int wBlocks = (N + 3) / 4;
    const int pBlocks = (E + PCHUNK - 1) / PCHUNK;   // 391

    // CSR build (bucketed, all dense / L2-hot)
    hipMemsetAsync(bucketCount, 0, NBMAX * sizeof(int), stream);
    bucket_count_kernel<<<512, 256, 0, stream>>>(dst, bucketCount, E);
    bucket_scan_kernel<<<1, NBMAX, 0, stream>>>(bucketCount, bucketBase, bucketCursor, NB);
    partition_kernel<<<pBlocks, 256, 0, stream>>>(src, dst, ew, bucketCursor, tmp, E);
    bucket_finalize_kernel<<<NB, 256, 0, stream>>>(bucketBase, tmp, comb, rowptr, dinv, N, NB);

    // layer 1
    gemm1_kernel<<<gBlocks, 256, 0, stream>>>(x, W1, dinv, B1, N);
    pull_kernel<<<wBlocks, 256, 0, stream>>>(rowptr, comb, B1, B2, N);

    // layer 2
    gemm2_kernel<<<gBlocks, 256, 0, stream>>>(B2, W2, dinv, b1, B1, N);
    pull_final_kernel<<<wBlocks, 256, 0, stream>>>(rowptr, comb, B1, dinv, b2, out, N);
}

// Round 12
// 445.120 us; speedup vs baseline: 1.6861x; 1.0378x over previous
//
#include <hip/hip_runtime.h>
#include <hip/hip_bf16.h>
#include <math.h>

// 2-layer GCN, N=100000, E=1.6M, DIN=256, HID=DOUT=64.
// R5: bucketed partition kills reorder's 8x write amplification.
// R8: CSR build collapsed to 4 bucket kernels.
// R9: pulls are traffic-bound at the random-gather fabric floor (FETCH 193MB =
//     8 XCD x full 25.6MB fp32 g-table, 2.84 TB/s). Unroll-8 was neutral.
// R10: g-tables stored as bf16 (128B/row) -> gather bytes halve. fp32 accum.

#define GCN_DIN 256
#define GCN_HID 64
#define PCHUNK 4096   // edges per partition block
#define NBMAX 256     // bucket capacity (actual = ceil(N/512) = 196)

__device__ __forceinline__ float bf2f(unsigned short u) {
    return __uint_as_float(((unsigned int)u) << 16);
}
__device__ __forceinline__ unsigned short f2bf(float f) {
    __hip_bfloat16 h = __float2bfloat16(f);   // RNE
    return *reinterpret_cast<unsigned short*>(&h);
}

// ---------- A: per-bucket edge histogram ----------
__global__ __launch_bounds__(256) void bucket_count_kernel(
    const int* __restrict__ dst, int* __restrict__ bucketCount, int E)
{
    __shared__ int h[NBMAX];
    for (int i = threadIdx.x; i < NBMAX; i += 256) h[i] = 0;
    __syncthreads();
    int stride = gridDim.x * 256;
    for (int e = blockIdx.x * 256 + threadIdx.x; e < E; e += stride)
        atomicAdd(&h[dst[e] >> 9], 1);
    __syncthreads();
    for (int i = threadIdx.x; i < NBMAX; i += 256)
        if (h[i]) atomicAdd(&bucketCount[i], h[i]);
}

// ---------- B: scan 196 bucket counts -> bucketBase, init cursors ----------
__global__ __launch_bounds__(NBMAX) void bucket_scan_kernel(
    const int* __restrict__ bucketCount, int* __restrict__ bucketBase,
    int* __restrict__ bucketCursor, int NB)
{
    __shared__ int s[NBMAX];
    int t = threadIdx.x;
    int v = (t < NB) ? bucketCount[t] : 0;
    s[t] = v;
    __syncthreads();
    for (int off = 1; off < NBMAX; off <<= 1) {
        int a = (t >= off) ? s[t - off] : 0;
        __syncthreads();
        s[t] += a;
        __syncthreads();
    }
    if (t < NB) { int ex = s[t] - v; bucketBase[t] = ex; bucketCursor[t] = ex; }
    if (t == NB - 1) bucketBase[NB] = s[t];
}

// ---------- C: partition edges into dst-range buckets (dense runs) ----------
__global__ __launch_bounds__(256) void partition_kernel(
    const int* __restrict__ src, const int* __restrict__ dst, const float* __restrict__ ew,
    int* __restrict__ bucketCursor, int2* __restrict__ tmp, int E)
{
    __shared__ int hcount[NBMAX];
    __shared__ int hbase[NBMAX];
    __shared__ int hoff[NBMAX];
    const int tid = threadIdx.x;
    const int b0 = blockIdx.x * PCHUNK;
    const int bend = (b0 + PCHUNK < E) ? (b0 + PCHUNK) : E;

    for (int i = tid; i < NBMAX; i += 256) { hcount[i] = 0; hoff[i] = 0; }
    __syncthreads();
    for (int e = b0 + tid; e < bend; e += 256)
        atomicAdd(&hcount[dst[e] >> 9], 1);
    __syncthreads();
    for (int i = tid; i < NBMAX; i += 256)
        if (hcount[i] > 0) hbase[i] = atomicAdd(&bucketCursor[i], hcount[i]);
    __syncthreads();
    for (int e = b0 + tid; e < bend; e += 256) {
        int d = dst[e];
        int b = d >> 9;
        int off = atomicAdd(&hoff[b], 1);
        int key = ((d & 511) << 17) | src[e];     // src < 2^17, local_dst < 2^9
        tmp[hbase[b] + off] = make_int2(key, __float_as_int(ew[e]));
    }
}

// ---------- D: per-bucket finalize: counts+ewsum -> rowptr+dinv, scatter comb ----------
__global__ __launch_bounds__(256) void bucket_finalize_kernel(
    const int* __restrict__ bucketBase, const int2* __restrict__ tmp,
    int2* __restrict__ comb, int* __restrict__ rowptr, float* __restrict__ dinv,
    int N, int NB)
{
    __shared__ int   cnt[512];
    __shared__ float ews[512];
    __shared__ int   sc[512];
    __shared__ int   cur[512];
    const int tid = threadIdx.x;
    const int b = blockIdx.x;
    const int base = b << 9;
    const int nn = (base + 512 < N) ? 512 : (N - base);
    for (int i = tid; i < 512; i += 256) { cnt[i] = 0; ews[i] = 0.f; }
    __syncthreads();
    const int jb = bucketBase[b], je = bucketBase[b + 1];
    for (int j = jb + tid; j < je; j += 256) {
        int2 t = tmp[j];
        int l = t.x >> 17;
        atomicAdd(&cnt[l], 1);
        atomicAdd(&ews[l], __int_as_float(t.y));
    }
    __syncthreads();
    for (int i = tid; i < 512; i += 256) sc[i] = cnt[i];
    __syncthreads();
    for (int off = 1; off < 512; off <<= 1) {
        int i0 = tid, i1 = tid + 256;
        int v0 = (i0 >= off) ? sc[i0 - off] : 0;
        int v1 = (i1 >= off) ? sc[i1 - off] : 0;
        __syncthreads();
        sc[i0] += v0; sc[i1] += v1;
        __syncthreads();
    }
    for (int i = tid; i < 512; i += 256) cur[i] = sc[i] - cnt[i];   // exclusive
    __syncthreads();
    for (int i = tid; i < nn; i += 256) {
        rowptr[base + i] = jb + cur[i];
        float s = 1.0f + ews[i];
        dinv[base + i] = (s > 0.f) ? (1.0f / sqrtf(s)) : 0.f;
    }
    if (b == NB - 1 && tid == 0) rowptr[N] = je;
    __syncthreads();
    for (int j = jb + tid; j < je; j += 256) {
        int2 t = tmp[j];
        int l = t.x >> 17;
        int pos = jb + atomicAdd(&cur[l], 1);
        comb[pos] = make_int2(t.x & 0x1FFFF, t.y);
    }
}

// ---------- GEMM1: g = bf16( dinv * (x @ W1) ), [N,256]x[256,64] ----------
__global__ __launch_bounds__(256) void gemm1_kernel(
    const float* __restrict__ x, const float* __restrict__ W,
    const float* __restrict__ dinv, unsigned short* __restrict__ g, int N)
{
    __shared__ float xs[32][68];
    __shared__ float ws[32][64];
    const int tid = threadIdx.x;
    const int tx = tid & 15;
    const int ty = tid >> 4;
    const int row0 = blockIdx.x * 64;

    float acc[4][4];
    #pragma unroll
    for (int i = 0; i < 4; ++i)
        #pragma unroll
        for (int j = 0; j < 4; ++j) acc[i][j] = 0.f;

    for (int k0 = 0; k0 < GCN_DIN; k0 += 32) {
        {
            int kc = tid & 7;
            int r  = tid >> 3;
            #pragma unroll
            for (int h = 0; h < 2; ++h) {
                int rr = r + 32 * h;
                int row = row0 + rr;
                float4 v = make_float4(0.f, 0.f, 0.f, 0.f);
                if (row < N) v = *(const float4*)&x[(size_t)row * GCN_DIN + k0 + kc * 4];
                xs[kc * 4 + 0][rr] = v.x;
                xs[kc * 4 + 1][rr] = v.y;
                xs[kc * 4 + 2][rr] = v.z;
                xs[kc * 4 + 3][rr] = v.w;
            }
        }
        {
            int c  = tid & 63;
            int kr = tid >> 6;
            #pragma unroll
            for (int h = 0; h < 8; ++h)
                ws[kr + 4 * h][c] = W[(size_t)(k0 + kr + 4 * h) * 64 + c];
        }
        __syncthreads();
        #pragma unroll
        for (int kk = 0; kk < 32; ++kk) {
            float4 a = *(const float4*)&xs[kk][ty * 4];
            float4 b = *(const float4*)&ws[kk][tx * 4];
            float av[4] = {a.x, a.y, a.z, a.w};
            float bv[4] = {b.x, b.y, b.z, b.w};
            #pragma unroll
            for (int i = 0; i < 4; ++i)
                #pragma unroll
                for (int j = 0; j < 4; ++j)
                    acc[i][j] = fmaf(av[i], bv[j], acc[i][j]);
        }
        __syncthreads();
    }
    #pragma unroll
    for (int i = 0; i < 4; ++i) {
        int row = row0 + ty * 4 + i;
        if (row < N) {
            float dv = dinv[row];
            ushort4 o;
            o.x = f2bf(dv * acc[i][0]);
            o.y = f2bf(dv * acc[i][1]);
            o.z = f2bf(dv * acc[i][2]);
            o.w = f2bf(dv * acc[i][3]);
            *(ushort4*)&g[(size_t)row * 64 + tx * 4] = o;
        }
    }
}

// ---------- GEMM2: g = bf16( dinv * (relu(dinv*acc1 + b1) @ W2) ), K=64 ----------
__global__ __launch_bounds__(256) void gemm2_kernel(
    const float* __restrict__ acc1, const float* __restrict__ W,
    const float* __restrict__ dinv, const float* __restrict__ b1,
    unsigned short* __restrict__ g, int N)
{
    __shared__ float xs[32][68];
    __shared__ float ws[32][64];
    const int tid = threadIdx.x;
    const int tx = tid & 15;
    const int ty = tid >> 4;
    const int row0 = blockIdx.x * 64;

    float acc[4][4];
    #pragma unroll
    for (int i = 0; i < 4; ++i)
        #pragma unroll
        for (int j = 0; j < 4; ++j) acc[i][j] = 0.f;

    for (int k0 = 0; k0 < GCN_HID; k0 += 32) {
        {
            int kc = tid & 7;
            int r  = tid >> 3;
            float4 bb = *(const float4*)&b1[k0 + kc * 4];
            #pragma unroll
            for (int h = 0; h < 2; ++h) {
                int rr = r + 32 * h;
                int row = row0 + rr;
                float4 v = make_float4(0.f, 0.f, 0.f, 0.f);
                if (row < N) {
                    float dv = dinv[row];
                    float4 hh = *(const float4*)&acc1[(size_t)row * 64 + k0 + kc * 4];
                    v.x = fmaxf(dv * hh.x + bb.x, 0.f);
                    v.y = fmaxf(dv * hh.y + bb.y, 0.f);
                    v.z = fmaxf(dv * hh.z + bb.z, 0.f);
                    v.w = fmaxf(dv * hh.w + bb.w, 0.f);
                }
                xs[kc * 4 + 0][rr] = v.x;
                xs[kc * 4 + 1][rr] = v.y;
                xs[kc * 4 + 2][rr] = v.z;
                xs[kc * 4 + 3][rr] = v.w;
            }
        }
        {
            int c  = tid & 63;
            int kr = tid >> 6;
            #pragma unroll
            for (int h = 0; h < 8; ++h)
                ws[kr + 4 * h][c] = W[(size_t)(k0 + kr + 4 * h) * 64 + c];
        }
        __syncthreads();
        #pragma unroll
        for (int kk = 0; kk < 32; ++kk) {
            float4 a = *(const float4*)&xs[kk][ty * 4];
            float4 b = *(const float4*)&ws[kk][tx * 4];
            float av[4] = {a.x, a.y, a.z, a.w};
            float bv[4] = {b.x, b.y, b.z, b.w};
            #pragma unroll
            for (int i = 0; i < 4; ++i)
                #pragma unroll
                for (int j = 0; j < 4; ++j)
                    acc[i][j] = fmaf(av[i], bv[j], acc[i][j]);
        }
        __syncthreads();
    }
    #pragma unroll
    for (int i = 0; i < 4; ++i) {
        int row = row0 + ty * 4 + i;
        if (row < N) {
            float dv = dinv[row];
            ushort4 o;
            o.x = f2bf(dv * acc[i][0]);
            o.y = f2bf(dv * acc[i][1]);
            o.z = f2bf(dv * acc[i][2]);
            o.w = f2bf(dv * acc[i][3]);
            *(ushort4*)&g[(size_t)row * 64 + tx * 4] = o;
        }
    }
}

// ---------- pull: out[n] = g[n] + sum_in ew * g[src]; wave/node, bf16 gathers ----------
__global__ __launch_bounds__(256) void pull_kernel(
    const int* __restrict__ rowptr, const int2* __restrict__ comb,
    const unsigned short* __restrict__ g, float* __restrict__ out, int N)
{
    int wid  = (blockIdx.x * blockDim.x + threadIdx.x) >> 6;
    int lane = threadIdx.x & 63;
    if (wid >= N) return;
    int jb = rowptr[wid], je = rowptr[wid + 1];
    float acc0 = bf2f(g[(size_t)wid * 64 + lane]);
    float acc1 = 0.f;
    int j = jb;
    for (; j + 3 < je; j += 4) {
        int2 e0 = comb[j], e1 = comb[j + 1], e2 = comb[j + 2], e3 = comb[j + 3];
        float v0 = bf2f(g[(size_t)e0.x * 64 + lane]);
        float v1 = bf2f(g[(size_t)e1.x * 64 + lane]);
        float v2 = bf2f(g[(size_t)e2.x * 64 + lane]);
        float v3 = bf2f(g[(size_t)e3.x * 64 + lane]);
        acc0 = fmaf(__int_as_float(e0.y), v0, acc0);
        acc1 = fmaf(__int_as_float(e1.y), v1, acc1);
        acc0 = fmaf(__int_as_float(e2.y), v2, acc0);
        acc1 = fmaf(__int_as_float(e3.y), v3, acc1);
    }
    for (; j < je; ++j) {
        int2 e0 = comb[j];
        acc0 = fmaf(__int_as_float(e0.y), bf2f(g[(size_t)e0.x * 64 + lane]), acc0);
    }
    out[(size_t)wid * 64 + lane] = acc0 + acc1;
}

// same, fused final epilogue: out = dinv[n]*acc + b2
__global__ __launch_bounds__(256) void pull_final_kernel(
    const int* __restrict__ rowptr, const int2* __restrict__ comb,
    const unsigned short* __restrict__ g, const float* __restrict__ dinv,
    const float* __restrict__ b2, float* __restrict__ out, int N)
{
    int wid  = (blockIdx.x * blockDim.x + threadIdx.x) >> 6;
    int lane = threadIdx.x & 63;
    if (wid >= N) return;
    int jb = rowptr[wid], je = rowptr[wid + 1];
    float acc0 = bf2f(g[(size_t)wid * 64 + lane]);
    float acc1 = 0.f;
    int j = jb;
    for (; j + 3 < je; j += 4) {
        int2 e0 = comb[j], e1 = comb[j + 1], e2 = comb[j + 2], e3 = comb[j + 3];
        float v0 = bf2f(g[(size_t)e0.x * 64 + lane]);
        float v1 = bf2f(g[(size_t)e1.x * 64 + lane]);
        float v2 = bf2f(g[(size_t)e2.x * 64 + lane]);
        float v3 = bf2f(g[(size_t)e3.x * 64 + lane]);
        acc0 = fmaf(__int_as_float(e0.y), v0, acc0);
        acc1 = fmaf(__int_as_float(e1.y), v1, acc1);
        acc0 = fmaf(__int_as_float(e2.y), v2, acc0);
        acc1 = fmaf(__int_as_float(e3.y), v3, acc1);
    }
    for (; j < je; ++j) {
        int2 e0 = comb[j];
        acc0 = fmaf(__int_as_float(e0.y), bf2f(g[(size_t)e0.x * 64 + lane]), acc0);
    }
    out[(size_t)wid * 64 + lane] = dinv[wid] * (acc0 + acc1) + b2[lane];
}

extern "C" void kernel_launch(void* const* d_in, const int* in_sizes, int n_in,
                              void* d_out, int out_size, void* d_ws, size_t ws_size,
                              hipStream_t stream) {
    const float* x  = (const float*)d_in[0];
    const int*   ei = (const int*)  d_in[1];
    const float* ew = (const float*)d_in[2];
    const float* W1 = (const float*)d_in[3];
    const float* b1 = (const float*)d_in[4];
    const float* W2 = (const float*)d_in[5];
    const float* b2 = (const float*)d_in[6];
    float* out = (float*)d_out;

    const int N = in_sizes[0] / GCN_DIN;   // 100000
    const int E = in_sizes[1] / 2;         // 1600000
    const int* src = ei;
    const int* dst = ei + E;
    const int NB = (N + 511) >> 9;         // 196 buckets

    // workspace: comb | G1(bf16, aliases tmp) | B2(fp32) | G2(bf16) | dinv | rowptr | buckets
    char* p = (char*)d_ws;
    int2*  comb = (int2*)p;            p += (size_t)E * sizeof(int2);
    unsigned short* G1 = (unsigned short*)p; p += (size_t)N * 64 * sizeof(unsigned short);
    // pad G1 region up to E*8 bytes (tmp needs E int2; N*64*2 = 12.8MB = E*8 here, but guard)
    {
        size_t g1b = (size_t)N * 64 * sizeof(unsigned short);
        size_t tmb = (size_t)E * sizeof(int2);
        if (tmb > g1b) p += (tmb - g1b);
    }
    float* B2   = (float*)p;           p += (size_t)N * 64 * sizeof(float);
    unsigned short* G2 = (unsigned short*)p; p += (size_t)N * 64 * sizeof(unsigned short);
    float* dinv = (float*)p;           p += (size_t)N * sizeof(float);
    int*   rowptr = (int*)p;           p += (size_t)(N + 1) * sizeof(int);
    int*   bucketCount  = (int*)p;     p += NBMAX * sizeof(int);
    int*   bucketBase   = (int*)p;     p += (NBMAX + 1) * sizeof(int);
    int*   bucketCursor = (int*)p;     p += NBMAX * sizeof(int);
    int2*  tmp = (int2*)G1;            // G1 dead until gemm1; finalize consumes tmp first

    const int gBlocks = (N + 63) / 64;
    const int wBlocks = (N + 3) / 4;
    const int pBlocks = (E + PCHUNK - 1) / PCHUNK;   // 391

    // CSR build (bucketed, all dense / L2-hot)
    hipMemsetAsync(bucketCount, 0, NBMAX * sizeof(int), stream);
    bucket_count_kernel<<<512, 256, 0, stream>>>(dst, bucketCount, E);
    bucket_scan_kernel<<<1, NBMAX, 0, stream>>>(bucketCount, bucketBase, bucketCursor, NB);
    partition_kernel<<<pBlocks, 256, 0, stream>>>(src, dst, ew, bucketCursor, tmp, E);
    bucket_finalize_kernel<<<NB, 256, 0, stream>>>(bucketBase, tmp, comb, rowptr, dinv, N, NB);

    // layer 1
    gemm1_kernel<<<gBlocks, 256, 0, stream>>>(x, W1, dinv, G1, N);
    pull_kernel<<<wBlocks, 256, 0, stream>>>(rowptr, comb, G1, B2, N);

    // layer 2
    gemm2_kernel<<<gBlocks, 256, 0, stream>>>(B2, W2, dinv, b1, G2, N);
    pull_final_kernel<<<wBlocks, 256, 0, stream>>>(rowptr, comb, G2, dinv, b2, out, N);
}